// Round 12
// baseline (222.543 us; speedup 1.0000x reference)
//
#include <hip/hip_runtime.h>
#include <hip/hip_bf16.h>

typedef _Float16 half_t;
typedef _Float16 f16x8 __attribute__((ext_vector_type(8)));
typedef float f32x4 __attribute__((ext_vector_type(4)));

#define AS1 __attribute__((address_space(1)))
#define AS3 __attribute__((address_space(3)))

constexpr int CB = 512;    // channels
constexpr int NB = 2048;   // sequence length
constexpr int BB = 8;      // batch

__device__ inline f32x4 mfma16(f16x8 a, f16x8 b, f32x4 c) {
  return __builtin_amdgcn_mfma_f32_16x16x32_f16(a, b, c, 0, 0, 0);
}

// ---------------- wv -> fp16
__global__ void convert_w(const float* __restrict__ wv, half_t* __restrict__ wvh) {
  int i = blockIdx.x * 256 + threadIdx.x;
  if (i < CB * CB) wvh[i] = (half_t)wv[i];
}

// ---------------- G partials: Gp[z][c][d] = sum_{o in chunk z} wq[o][c]*wk[o][d]
__global__ __launch_bounds__(256) void compute_G_part(const float* __restrict__ wq,
                                                      const float* __restrict__ wk,
                                                      float* __restrict__ Gp) {
  __shared__ float aq[64][68];
  __shared__ float ak[64][68];
  const int c0 = blockIdx.y * 64, d0 = blockIdx.x * 64, o0 = blockIdx.z * 64;
  const int t = threadIdx.x;
  {
    const int r = t >> 2, cbase = (t & 3) * 16;
    const float* q = wq + (size_t)(o0 + r) * CB + c0 + cbase;
    const float* k = wk + (size_t)(o0 + r) * CB + d0 + cbase;
#pragma unroll
    for (int q4 = 0; q4 < 4; q4++) {
      *(float4*)&aq[r][cbase + q4 * 4] = *(const float4*)(q + q4 * 4);
      *(float4*)&ak[r][cbase + q4 * 4] = *(const float4*)(k + q4 * 4);
    }
  }
  __syncthreads();
  const int tc = t & 15, td = t >> 4;
  float acc[4][4] = {};
#pragma unroll 8
  for (int o = 0; o < 64; o++) {
    float4 a4 = *(const float4*)&aq[o][tc * 4];
    float4 b4 = *(const float4*)&ak[o][td * 4];
    float av[4] = {a4.x, a4.y, a4.z, a4.w};
    float bv[4] = {b4.x, b4.y, b4.z, b4.w};
#pragma unroll
    for (int i = 0; i < 4; i++)
#pragma unroll
      for (int j = 0; j < 4; j++)
        acc[i][j] += av[i] * bv[j];
  }
  float* gz = Gp + (size_t)blockIdx.z * CB * CB;
#pragma unroll
  for (int i = 0; i < 4; i++) {
    int c = c0 + tc * 4 + i;
#pragma unroll
    for (int j = 0; j < 4; j++)
      gz[(size_t)c * CB + d0 + td * 4 + j] = acc[i][j];
  }
}

// ---------------- reduce 8 partials -> G fp16
__global__ void reduce_G(const float* __restrict__ Gp, half_t* __restrict__ Gh) {
  int i = blockIdx.x * 256 + threadIdx.x;
  if (i >= CB * CB) return;
  float s = 0.0f;
#pragma unroll
  for (int z = 0; z < 8; z++) s += Gp[(size_t)z * CB * CB + i];
  Gh[i] = (half_t)s;
}

// ---------------- u[d] = sum_o bq[o]*wk[o][d]
__global__ void compute_u(const float* __restrict__ wk, const float* __restrict__ bq,
                          float* __restrict__ u) {
  int d = blockIdx.x * 256 + threadIdx.x;
  if (d >= CB) return;
  float s = 0.0f;
  for (int o = 0; o < CB; o++) s += bq[o] * wk[(size_t)o * CB + d];
  u[d] = s;
}

// ---------------- ubias[row] = sum_c u[c] * xh[row][c], row in [0, B*N)
__global__ __launch_bounds__(256) void compute_ubias(const half_t* __restrict__ xh,
                                                     const float* __restrict__ u,
                                                     float* __restrict__ ub) {
  __shared__ float us[CB];
  for (int i = threadIdx.x; i < CB; i += 256) us[i] = u[i];
  __syncthreads();
  int row = blockIdx.x * 4 + (threadIdx.x >> 6);
  int lane = threadIdx.x & 63;
  f16x8 vh = *(const f16x8*)(xh + (size_t)row * CB + lane * 8);
  float s = 0.0f;
#pragma unroll
  for (int i = 0; i < 8; i++) s += us[lane * 8 + i] * (float)vh[i];
#pragma unroll
  for (int off = 32; off; off >>= 1) s += __shfl_xor(s, off);
  if (lane == 0) ub[row] = s;
}

// ---------------- x [B][C][N] fp32 -> xh [B][N][C] fp16 (transpose) + xn [B][C][N] fp16
__global__ void transpose_x(const float* __restrict__ x, half_t* __restrict__ oh,
                            half_t* __restrict__ xn) {
  __shared__ float tile[32][33];
  int b = blockIdx.z, c0 = blockIdx.y * 32, n0 = blockIdx.x * 32;
  int tx = threadIdx.x, ty = threadIdx.y;          // block (32, 8)
  const float* xb = x + (size_t)b * CB * NB;
  half_t* xnb = xn + (size_t)b * CB * NB;
#pragma unroll
  for (int r = 0; r < 4; r++) {
    float v = xb[(size_t)(c0 + ty + 8 * r) * NB + n0 + tx];
    tile[ty + 8 * r][tx] = v;
    xnb[(size_t)(c0 + ty + 8 * r) * NB + n0 + tx] = (half_t)v;
  }
  __syncthreads();
  size_t base = (size_t)b * NB * CB;
#pragma unroll
  for (int r = 0; r < 4; r++)
    oh[base + (size_t)(n0 + ty + 8 * r) * CB + c0 + tx] = (half_t)tile[tx][ty + 8 * r];
}

// ---------------- GEMM-NT (proven 128^2 2-barrier, fp16):  D[M][N] = A[M][K] * B[N][K]^T
// BSPLIT: 1 -> B hi/lo planes, 2 MFMA passes. BIAS: 0 none, 1 batched col-bias, 2 row-bias
// EPI: 0 f32; 1 fp16; 4 int16 fixed-point (val*256, clamped)
template <int BIAS, int EPI, int BSPLIT>
__global__ __launch_bounds__(256) void gemm_nt(
    const half_t* __restrict__ A, int lda, long sA,
    const half_t* __restrict__ Bh, const half_t* __restrict__ Bl, int ldb, long sB,
    void* __restrict__ D, int ldd, long sD,
    const float* __restrict__ bias, long sBias,
    int K) {
  constexpr int PL = 2 + BSPLIT;
  constexpr int TSZ = 128 * 32;
  __shared__ alignas(16) half_t sm[2 * PL * TSZ];

  const int t = threadIdx.x;
  const int z = blockIdx.z;
  const half_t* Ab  = A  + (size_t)z * sA + (size_t)(blockIdx.y * 128) * lda;
  const half_t* Bbh = Bh + (size_t)z * sB + (size_t)(blockIdx.x * 128) * ldb;
  const half_t* Bbl = BSPLIT ? Bl + (size_t)z * sB + (size_t)(blockIdx.x * 128) * ldb : nullptr;
  const int wid = t >> 6, l15 = t & 15, hi = (t >> 4) & 3;
  const int wr = wid >> 1, wc = wid & 1;
  const int lineA = t >> 2, eoff = (t & 3) * 8;

  f32x4 acc[4][4] = {};

  auto stage = [&](int buf, int kt) {
    half_t* base = sm + buf * (PL * TSZ);
#pragma unroll
    for (int p = 0; p < 2; p++) {
      size_t goA = (size_t)(p * 64 + lineA) * lda + kt * 32 + eoff;
      size_t goB = (size_t)(p * 64 + lineA) * ldb + kt * 32 + eoff;
      int lo = p * 2048 + t * 8;
      __builtin_amdgcn_global_load_lds((const AS1 void*)(Ab + goA),  (AS3 void*)(base + lo), 16, 0, 0);
      __builtin_amdgcn_global_load_lds((const AS1 void*)(Bbh + goB), (AS3 void*)(base + TSZ + lo), 16, 0, 0);
      if (BSPLIT)
        __builtin_amdgcn_global_load_lds((const AS1 void*)(Bbl + goB), (AS3 void*)(base + 2 * TSZ + lo), 16, 0, 0);
    }
  };

  const int nt = K >> 5;
  stage(0, 0);
  __syncthreads();
  int cur = 0;
  for (int kt = 0; kt < nt; kt++) {
    if (kt + 1 < nt) stage(cur ^ 1, kt + 1);
    const half_t* bb = sm + cur * (PL * TSZ);
    f16x8 af[4], bfh[4], bfl[4];
#pragma unroll
    for (int f = 0; f < 4; f++) {
      int ao = (wr * 64 + f * 16 + l15) * 32 + hi * 8;
      int bo = (wc * 64 + f * 16 + l15) * 32 + hi * 8;
      af[f]  = *(const f16x8*)(bb + ao);
      bfh[f] = *(const f16x8*)(bb + TSZ + bo);
      if (BSPLIT) bfl[f] = *(const f16x8*)(bb + 2 * TSZ + bo);
    }
#pragma unroll
    for (int pass = 0; pass < 1 + BSPLIT; pass++) {
#pragma unroll
      for (int fm = 0; fm < 4; fm++)
#pragma unroll
        for (int fn = 0; fn < 4; fn++)
          acc[fm][fn] = mfma16(af[fm], (pass == 1) ? bfl[fn] : bfh[fn], acc[fm][fn]);
    }
    __syncthreads();
    cur ^= 1;
  }

  const int row0 = blockIdx.y * 128 + wr * 64;
  const int col0 = blockIdx.x * 128 + wc * 64;
#pragma unroll
  for (int fm = 0; fm < 4; fm++) {
    int rowb = row0 + fm * 16 + hi * 4;
#pragma unroll
    for (int fn = 0; fn < 4; fn++) {
      int col = col0 + fn * 16 + l15;
      float bc = (BIAS == 1) ? bias[(size_t)z * sBias + col] : 0.0f;
#pragma unroll
      for (int r = 0; r < 4; r++) {
        float val = acc[fm][fn][r] + bc;
        if (BIAS == 2) val += bias[(size_t)z * sBias + rowb + r];
        size_t di = (size_t)(rowb + r) * ldd + col;
        if (EPI == 0) {
          ((float*)D)[(size_t)z * sD + di] = val;
        } else if (EPI == 1) {
          ((half_t*)D)[(size_t)z * sD + di] = (half_t)val;
        } else {  // EPI == 4: int16 fixed-point, scale 256
          float sv = fminf(fmaxf(val * 256.0f, -32767.0f), 32767.0f);
          ((short*)D)[(size_t)z * sD + di] = (short)__float2int_rn(sv);
        }
      }
    }
  }
}

// ---------------- PV GEMM: 128x64 tile, 2-barrier dbuf. out = v * Pd^T + xn (fp16 residual)
// grid (32, 4, 8): 64-col tiles of out; 4 waves 2x2, each 64 rows x 32 cols (acc[4][2]).
__global__ __launch_bounds__(256) void gemm_pv(
    const half_t* __restrict__ V, const half_t* __restrict__ P,
    const half_t* __restrict__ Rn, float* __restrict__ D) {
  constexpr int ATSZ = 128 * 32;    // 8 KB
  constexpr int BTSZ = 64 * 32;     // 4 KB
  constexpr int BUF = ATSZ + BTSZ;  // 6144 elems
  __shared__ alignas(16) half_t sm[2 * BUF];

  const int t = threadIdx.x, z = blockIdx.z;
  const half_t* Ab = V + (size_t)z * CB * NB + (size_t)(blockIdx.y * 128) * NB;
  const half_t* Bb = P + (size_t)z * NB * NB + (size_t)(blockIdx.x * 64) * NB;
  const int wid = t >> 6, l15 = t & 15, hi = (t >> 4) & 3;
  const int wr = wid >> 1, wc = wid & 1;
  const int lineA = t >> 2, eoff = (t & 3) * 8;

  f32x4 acc[4][2] = {};

  auto stage = [&](int buf, int kt) {
    half_t* base = sm + buf * BUF;
#pragma unroll
    for (int p = 0; p < 2; p++) {
      size_t go = (size_t)(p * 64 + lineA) * NB + kt * 32 + eoff;
      __builtin_amdgcn_global_load_lds((const AS1 void*)(Ab + go),
                                       (AS3 void*)(base + p * 2048 + t * 8), 16, 0, 0);
    }
    size_t gb = (size_t)lineA * NB + kt * 32 + eoff;
    __builtin_amdgcn_global_load_lds((const AS1 void*)(Bb + gb),
                                     (AS3 void*)(base + ATSZ + t * 8), 16, 0, 0);
  };

  stage(0, 0);
  __syncthreads();
  int cur = 0;
  for (int kt = 0; kt < 64; kt++) {
    if (kt + 1 < 64) stage(cur ^ 1, kt + 1);
    const half_t* bb = sm + cur * BUF;
    f16x8 af[4], bf[2];
#pragma unroll
    for (int f = 0; f < 4; f++)
      af[f] = *(const f16x8*)(bb + (wr * 64 + f * 16 + l15) * 32 + hi * 8);
#pragma unroll
    for (int f = 0; f < 2; f++)
      bf[f] = *(const f16x8*)(bb + ATSZ + (wc * 32 + f * 16 + l15) * 32 + hi * 8);
#pragma unroll
    for (int fm = 0; fm < 4; fm++)
#pragma unroll
      for (int fn = 0; fn < 2; fn++)
        acc[fm][fn] = mfma16(af[fm], bf[fn], acc[fm][fn]);
    __syncthreads();
    cur ^= 1;
  }

  const int row0 = blockIdx.y * 128 + wr * 64;
  const int col0 = blockIdx.x * 64 + wc * 32;
  float* Dz = D + (size_t)z * CB * NB;
  const half_t* Rz = Rn + (size_t)z * CB * NB;
#pragma unroll
  for (int fm = 0; fm < 4; fm++) {
    int rowb = row0 + fm * 16 + hi * 4;
#pragma unroll
    for (int fn = 0; fn < 2; fn++) {
      int col = col0 + fn * 16 + l15;
#pragma unroll
      for (int r = 0; r < 4; r++)
        Dz[(size_t)(rowb + r) * NB + col] =
            acc[fm][fn][r] + (float)Rz[(size_t)(rowb + r) * NB + col];
    }
  }
}

// ---------------- row softmax over S int16 [rows][2048] (scale 1/256); writes dense P fp16
struct alignas(16) H8 { half_t h[8]; };
struct alignas(16) S8 { short s[8]; };

__global__ __launch_bounds__(256) void softmax_rows(const short* __restrict__ S,
                                                    half_t* __restrict__ P) {
  const short* row = S + (size_t)blockIdx.x * NB;
  int t = threadIdx.x;
  S8 r8 = *reinterpret_cast<const S8*>(row + t * 8);
  float vals[8];
#pragma unroll
  for (int i = 0; i < 8; i++) vals[i] = (float)r8.s[i] * 0.00390625f;
  float m = vals[0];
#pragma unroll
  for (int i = 1; i < 8; i++) m = fmaxf(m, vals[i]);
#pragma unroll
  for (int off = 32; off; off >>= 1) m = fmaxf(m, __shfl_xor(m, off));
  __shared__ float redm[4], reds[4];
  if ((t & 63) == 0) redm[t >> 6] = m;
  __syncthreads();
  m = fmaxf(fmaxf(redm[0], redm[1]), fmaxf(redm[2], redm[3]));
  float e[8], s = 0.0f;
#pragma unroll
  for (int i = 0; i < 8; i++) { e[i] = __expf(vals[i] - m); s += e[i]; }
#pragma unroll
  for (int off = 32; off; off >>= 1) s += __shfl_xor(s, off);
  if ((t & 63) == 0) reds[t >> 6] = s;
  __syncthreads();
  s = reds[0] + reds[1] + reds[2] + reds[3];
  float inv = 1.0f / s;
  H8 ob;
#pragma unroll
  for (int i = 0; i < 8; i++) ob.h[i] = (half_t)(e[i] * inv);
  *reinterpret_cast<H8*>(P + (size_t)blockIdx.x * NB + t * 8) = ob;
}

// ---------------- launcher
extern "C" void kernel_launch(void* const* d_in, const int* in_sizes, int n_in,
                              void* d_out, int out_size, void* d_ws, size_t ws_size,
                              hipStream_t stream) {
  const float* x  = (const float*)d_in[0];
  const float* wq = (const float*)d_in[1];
  const float* bq = (const float*)d_in[2];
  const float* wk = (const float*)d_in[3];
  const float* wv = (const float*)d_in[5];
  const float* bv = (const float*)d_in[6];
  float* out = (float*)d_out;

  const size_t MB = 1u << 20;
  if (ws_size < 196 * MB) return;

  char* ws = (char*)d_ws;
  half_t* xh   = (half_t*)(ws + 0);            // [B][N][C]    16 MB
  half_t* YTh  = (half_t*)(ws + 16 * MB);      // [B][N][C]    16 MB
  half_t* v    = (half_t*)(ws + 32 * MB);      // [B][C][N]    16 MB
  short*  Ss   = (short*)(ws + 48 * MB);       // [8][N][N]    64 MB (int16 logits, scale 256)
  float*  Gp   = (float*)(ws + 48 * MB);       // [8][C][C]     8 MB (overlay; dead before S)
  half_t* Pd   = (half_t*)(ws + 112 * MB);     // [8][N][N]    64 MB (dense P)
  half_t* xn   = (half_t*)(ws + 176 * MB);     // [B][C][N]    16 MB (fp16 residual copy)
  half_t* Gh   = (half_t*)(ws + 192 * MB);     // [C][C]      0.5 MB
  half_t* wvh  = (half_t*)(ws + 192 * MB + 512 * 1024);  // [C][C]  0.5 MB
  float*  u    = (float*)(ws + 193 * MB);                // [C]       2 KB
  float*  ub   = (float*)(ws + 193 * MB + 256 * 1024);   // [B][N]   64 KB

  convert_w<<<1024, 256, 0, stream>>>(wv, wvh);
  compute_G_part<<<dim3(8, 8, 8), 256, 0, stream>>>(wq, wk, Gp);
  reduce_G<<<1024, 256, 0, stream>>>(Gp, Gh);
  compute_u<<<2, 256, 0, stream>>>(wk, bq, u);
  transpose_x<<<dim3(64, 16, 8), dim3(32, 8), 0, stream>>>(x, xh, xn);
  compute_ubias<<<BB * NB / 4, 256, 0, stream>>>(xh, u, ub);

  // YT[b][j][c] = sum_d xh[b][j][d] * G[c][d]   (single-pass fp16)
  gemm_nt<0, 1, 0><<<dim3(4, 16, 8), 256, 0, stream>>>(
      xh, CB, (long)NB * CB, Gh, nullptr, CB, 0,
      YTh, CB, (long)NB * CB, nullptr, 0, CB);

  // v[b][c][n] = sum_cin wv[c][cin]*x[b][cin][n] + bv[c]
  gemm_nt<2, 1, 0><<<dim3(16, 4, 8), 256, 0, stream>>>(
      wvh, CB, 0, xh, nullptr, CB, (long)NB * CB,
      v, NB, (long)CB * NB, bv, 0, CB);

  // S[z][i][j] = sum_c xh[i][c]*YTh[j][c] + ub[z][j]  -> int16 (scale 256)
  gemm_nt<1, 4, 0><<<dim3(16, 16, 8), 256, 0, stream>>>(
      xh, CB, (long)NB * CB,
      YTh, nullptr, CB, (long)NB * CB,
      Ss, NB, (long)NB * NB, ub, NB, CB);

  softmax_rows<<<BB * NB, 256, 0, stream>>>(Ss, Pd);

  // out[z][ch][i] = sum_j v[z][ch][j]*Pd[z][i][j] + xn[z][ch][i]   (128x64 tile)
  gemm_pv<<<dim3(32, 4, 8), 256, 0, stream>>>(v, Pd, xn, out);
}

// Round 13
// 211.718 us; speedup vs baseline: 1.0511x; 1.0511x over previous
//
#include <hip/hip_runtime.h>
#include <hip/hip_bf16.h>

typedef _Float16 half_t;
typedef _Float16 f16x8 __attribute__((ext_vector_type(8)));
typedef float f32x4 __attribute__((ext_vector_type(4)));

#define AS1 __attribute__((address_space(1)))
#define AS3 __attribute__((address_space(3)))

constexpr int CB = 512;    // channels
constexpr int NB = 2048;   // sequence length
constexpr int BB = 8;      // batch

__device__ inline f32x4 mfma16(f16x8 a, f16x8 b, f32x4 c) {
  return __builtin_amdgcn_mfma_f32_16x16x32_f16(a, b, c, 0, 0, 0);
}

// ---------------- wv -> fp16
__global__ void convert_w(const float* __restrict__ wv, half_t* __restrict__ wvh) {
  int i = blockIdx.x * 256 + threadIdx.x;
  if (i < CB * CB) wvh[i] = (half_t)wv[i];
}

// ---------------- G partials: Gp[z][c][d] = sum_{o in chunk z} wq[o][c]*wk[o][d]
__global__ __launch_bounds__(256) void compute_G_part(const float* __restrict__ wq,
                                                      const float* __restrict__ wk,
                                                      float* __restrict__ Gp) {
  __shared__ float aq[64][68];
  __shared__ float ak[64][68];
  const int c0 = blockIdx.y * 64, d0 = blockIdx.x * 64, o0 = blockIdx.z * 64;
  const int t = threadIdx.x;
  {
    const int r = t >> 2, cbase = (t & 3) * 16;
    const float* q = wq + (size_t)(o0 + r) * CB + c0 + cbase;
    const float* k = wk + (size_t)(o0 + r) * CB + d0 + cbase;
#pragma unroll
    for (int q4 = 0; q4 < 4; q4++) {
      *(float4*)&aq[r][cbase + q4 * 4] = *(const float4*)(q + q4 * 4);
      *(float4*)&ak[r][cbase + q4 * 4] = *(const float4*)(k + q4 * 4);
    }
  }
  __syncthreads();
  const int tc = t & 15, td = t >> 4;
  float acc[4][4] = {};
#pragma unroll 8
  for (int o = 0; o < 64; o++) {
    float4 a4 = *(const float4*)&aq[o][tc * 4];
    float4 b4 = *(const float4*)&ak[o][td * 4];
    float av[4] = {a4.x, a4.y, a4.z, a4.w};
    float bv[4] = {b4.x, b4.y, b4.z, b4.w};
#pragma unroll
    for (int i = 0; i < 4; i++)
#pragma unroll
      for (int j = 0; j < 4; j++)
        acc[i][j] += av[i] * bv[j];
  }
  float* gz = Gp + (size_t)blockIdx.z * CB * CB;
#pragma unroll
  for (int i = 0; i < 4; i++) {
    int c = c0 + tc * 4 + i;
#pragma unroll
    for (int j = 0; j < 4; j++)
      gz[(size_t)c * CB + d0 + td * 4 + j] = acc[i][j];
  }
}

// ---------------- reduce 8 partials -> G fp16
__global__ void reduce_G(const float* __restrict__ Gp, half_t* __restrict__ Gh) {
  int i = blockIdx.x * 256 + threadIdx.x;
  if (i >= CB * CB) return;
  float s = 0.0f;
#pragma unroll
  for (int z = 0; z < 8; z++) s += Gp[(size_t)z * CB * CB + i];
  Gh[i] = (half_t)s;
}

// ---------------- u[d] = sum_o bq[o]*wk[o][d]
__global__ void compute_u(const float* __restrict__ wk, const float* __restrict__ bq,
                          float* __restrict__ u) {
  int d = blockIdx.x * 256 + threadIdx.x;
  if (d >= CB) return;
  float s = 0.0f;
  for (int o = 0; o < CB; o++) s += bq[o] * wk[(size_t)o * CB + d];
  u[d] = s;
}

// ---------------- ubias[row] = sum_c u[c] * xh[row][c], row in [0, B*N)
__global__ __launch_bounds__(256) void compute_ubias(const half_t* __restrict__ xh,
                                                     const float* __restrict__ u,
                                                     float* __restrict__ ub) {
  __shared__ float us[CB];
  for (int i = threadIdx.x; i < CB; i += 256) us[i] = u[i];
  __syncthreads();
  int row = blockIdx.x * 4 + (threadIdx.x >> 6);
  int lane = threadIdx.x & 63;
  f16x8 vh = *(const f16x8*)(xh + (size_t)row * CB + lane * 8);
  float s = 0.0f;
#pragma unroll
  for (int i = 0; i < 8; i++) s += us[lane * 8 + i] * (float)vh[i];
#pragma unroll
  for (int off = 32; off; off >>= 1) s += __shfl_xor(s, off);
  if (lane == 0) ub[row] = s;
}

// ---------------- x [B][C][N] fp32 -> xh [B][N][C] fp16 (transpose) + xn [B][C][N] fp16
__global__ void transpose_x(const float* __restrict__ x, half_t* __restrict__ oh,
                            half_t* __restrict__ xn) {
  __shared__ float tile[32][33];
  int b = blockIdx.z, c0 = blockIdx.y * 32, n0 = blockIdx.x * 32;
  int tx = threadIdx.x, ty = threadIdx.y;          // block (32, 8)
  const float* xb = x + (size_t)b * CB * NB;
  half_t* xnb = xn + (size_t)b * CB * NB;
#pragma unroll
  for (int r = 0; r < 4; r++) {
    float v = xb[(size_t)(c0 + ty + 8 * r) * NB + n0 + tx];
    tile[ty + 8 * r][tx] = v;
    xnb[(size_t)(c0 + ty + 8 * r) * NB + n0 + tx] = (half_t)v;
  }
  __syncthreads();
  size_t base = (size_t)b * NB * CB;
#pragma unroll
  for (int r = 0; r < 4; r++)
    oh[base + (size_t)(n0 + ty + 8 * r) * CB + c0 + tx] = (half_t)tile[tx][ty + 8 * r];
}

// ---------------- GEMM-NT (proven 128^2 2-barrier, fp16):  D[M][N] = A[M][K] * B[N][K]^T
// BSPLIT: 1 -> B hi/lo planes, 2 MFMA passes. BIAS: 0 none, 1 batched col-bias, 2 row-bias
// EPI: 0 f32; 1 fp16; 3 f32 + fp16 residual R; 4 int16 fixed-point (val*256, clamped)
template <int BIAS, int EPI, int BSPLIT>
__global__ __launch_bounds__(256) void gemm_nt(
    const half_t* __restrict__ A, int lda, long sA,
    const half_t* __restrict__ Bh, const half_t* __restrict__ Bl, int ldb, long sB,
    void* __restrict__ D, int ldd, long sD,
    const float* __restrict__ bias, long sBias,
    const half_t* __restrict__ R, int ldr, long sR,
    int K) {
  constexpr int PL = 2 + BSPLIT;
  constexpr int TSZ = 128 * 32;
  __shared__ alignas(16) half_t sm[2 * PL * TSZ];

  const int t = threadIdx.x;
  const int z = blockIdx.z;
  const half_t* Ab  = A  + (size_t)z * sA + (size_t)(blockIdx.y * 128) * lda;
  const half_t* Bbh = Bh + (size_t)z * sB + (size_t)(blockIdx.x * 128) * ldb;
  const half_t* Bbl = BSPLIT ? Bl + (size_t)z * sB + (size_t)(blockIdx.x * 128) * ldb : nullptr;
  const int wid = t >> 6, l15 = t & 15, hi = (t >> 4) & 3;
  const int wr = wid >> 1, wc = wid & 1;
  const int lineA = t >> 2, eoff = (t & 3) * 8;

  f32x4 acc[4][4] = {};

  auto stage = [&](int buf, int kt) {
    half_t* base = sm + buf * (PL * TSZ);
#pragma unroll
    for (int p = 0; p < 2; p++) {
      size_t goA = (size_t)(p * 64 + lineA) * lda + kt * 32 + eoff;
      size_t goB = (size_t)(p * 64 + lineA) * ldb + kt * 32 + eoff;
      int lo = p * 2048 + t * 8;
      __builtin_amdgcn_global_load_lds((const AS1 void*)(Ab + goA),  (AS3 void*)(base + lo), 16, 0, 0);
      __builtin_amdgcn_global_load_lds((const AS1 void*)(Bbh + goB), (AS3 void*)(base + TSZ + lo), 16, 0, 0);
      if (BSPLIT)
        __builtin_amdgcn_global_load_lds((const AS1 void*)(Bbl + goB), (AS3 void*)(base + 2 * TSZ + lo), 16, 0, 0);
    }
  };

  const int nt = K >> 5;
  stage(0, 0);
  __syncthreads();
  int cur = 0;
  for (int kt = 0; kt < nt; kt++) {
    if (kt + 1 < nt) stage(cur ^ 1, kt + 1);
    const half_t* bb = sm + cur * (PL * TSZ);
    f16x8 af[4], bfh[4], bfl[4];
#pragma unroll
    for (int f = 0; f < 4; f++) {
      int ao = (wr * 64 + f * 16 + l15) * 32 + hi * 8;
      int bo = (wc * 64 + f * 16 + l15) * 32 + hi * 8;
      af[f]  = *(const f16x8*)(bb + ao);
      bfh[f] = *(const f16x8*)(bb + TSZ + bo);
      if (BSPLIT) bfl[f] = *(const f16x8*)(bb + 2 * TSZ + bo);
    }
#pragma unroll
    for (int pass = 0; pass < 1 + BSPLIT; pass++) {
#pragma unroll
      for (int fm = 0; fm < 4; fm++)
#pragma unroll
        for (int fn = 0; fn < 4; fn++)
          acc[fm][fn] = mfma16(af[fm], (pass == 1) ? bfl[fn] : bfh[fn], acc[fm][fn]);
    }
    __syncthreads();
    cur ^= 1;
  }

  const int row0 = blockIdx.y * 128 + wr * 64;
  const int col0 = blockIdx.x * 128 + wc * 64;
#pragma unroll
  for (int fm = 0; fm < 4; fm++) {
    int rowb = row0 + fm * 16 + hi * 4;
#pragma unroll
    for (int fn = 0; fn < 4; fn++) {
      int col = col0 + fn * 16 + l15;
      float bc = (BIAS == 1) ? bias[(size_t)z * sBias + col] : 0.0f;
#pragma unroll
      for (int r = 0; r < 4; r++) {
        float val = acc[fm][fn][r] + bc;
        if (BIAS == 2) val += bias[(size_t)z * sBias + rowb + r];
        size_t di = (size_t)(rowb + r) * ldd + col;
        if (EPI == 0) {
          ((float*)D)[(size_t)z * sD + di] = val;
        } else if (EPI == 1) {
          ((half_t*)D)[(size_t)z * sD + di] = (half_t)val;
        } else if (EPI == 3) {
          val += (float)R[(size_t)z * sR + (size_t)(rowb + r) * ldr + col];
          ((float*)D)[(size_t)z * sD + di] = val;
        } else {  // EPI == 4: int16 fixed-point, scale 256
          float sv = fminf(fmaxf(val * 256.0f, -32767.0f), 32767.0f);
          ((short*)D)[(size_t)z * sD + di] = (short)__float2int_rn(sv);
        }
      }
    }
  }
}

// ---------------- row softmax over S int16 [rows][2048] (scale 1/256); writes dense P fp16
struct alignas(16) H8 { half_t h[8]; };
struct alignas(16) S8 { short s[8]; };

__global__ __launch_bounds__(256) void softmax_rows(const short* __restrict__ S,
                                                    half_t* __restrict__ P) {
  const short* row = S + (size_t)blockIdx.x * NB;
  int t = threadIdx.x;
  S8 r8 = *reinterpret_cast<const S8*>(row + t * 8);
  float vals[8];
#pragma unroll
  for (int i = 0; i < 8; i++) vals[i] = (float)r8.s[i] * 0.00390625f;
  float m = vals[0];
#pragma unroll
  for (int i = 1; i < 8; i++) m = fmaxf(m, vals[i]);
#pragma unroll
  for (int off = 32; off; off >>= 1) m = fmaxf(m, __shfl_xor(m, off));
  __shared__ float redm[4], reds[4];
  if ((t & 63) == 0) redm[t >> 6] = m;
  __syncthreads();
  m = fmaxf(fmaxf(redm[0], redm[1]), fmaxf(redm[2], redm[3]));
  float e[8], s = 0.0f;
#pragma unroll
  for (int i = 0; i < 8; i++) { e[i] = __expf(vals[i] - m); s += e[i]; }
#pragma unroll
  for (int off = 32; off; off >>= 1) s += __shfl_xor(s, off);
  if ((t & 63) == 0) reds[t >> 6] = s;
  __syncthreads();
  s = reds[0] + reds[1] + reds[2] + reds[3];
  float inv = 1.0f / s;
  H8 ob;
#pragma unroll
  for (int i = 0; i < 8; i++) ob.h[i] = (half_t)(e[i] * inv);
  *reinterpret_cast<H8*>(P + (size_t)blockIdx.x * NB + t * 8) = ob;
}

// ---------------- launcher
extern "C" void kernel_launch(void* const* d_in, const int* in_sizes, int n_in,
                              void* d_out, int out_size, void* d_ws, size_t ws_size,
                              hipStream_t stream) {
  const float* x  = (const float*)d_in[0];
  const float* wq = (const float*)d_in[1];
  const float* bq = (const float*)d_in[2];
  const float* wk = (const float*)d_in[3];
  const float* wv = (const float*)d_in[5];
  const float* bv = (const float*)d_in[6];
  float* out = (float*)d_out;

  const size_t MB = 1u << 20;
  if (ws_size < 196 * MB) return;

  char* ws = (char*)d_ws;
  half_t* xh   = (half_t*)(ws + 0);            // [B][N][C]    16 MB
  half_t* YTh  = (half_t*)(ws + 16 * MB);      // [B][N][C]    16 MB
  half_t* v    = (half_t*)(ws + 32 * MB);      // [B][C][N]    16 MB
  short*  Ss   = (short*)(ws + 48 * MB);       // [8][N][N]    64 MB (int16 logits, scale 256)
  float*  Gp   = (float*)(ws + 48 * MB);       // [8][C][C]     8 MB (overlay; dead before S)
  half_t* Pd   = (half_t*)(ws + 112 * MB);     // [8][N][N]    64 MB (dense P)
  half_t* xn   = (half_t*)(ws + 176 * MB);     // [B][C][N]    16 MB (fp16 residual copy)
  half_t* Gh   = (half_t*)(ws + 192 * MB);     // [C][C]      0.5 MB
  half_t* wvh  = (half_t*)(ws + 192 * MB + 512 * 1024);  // [C][C]  0.5 MB
  float*  u    = (float*)(ws + 193 * MB);                // [C]       2 KB
  float*  ub   = (float*)(ws + 193 * MB + 256 * 1024);   // [B][N]   64 KB

  convert_w<<<1024, 256, 0, stream>>>(wv, wvh);
  compute_G_part<<<dim3(8, 8, 8), 256, 0, stream>>>(wq, wk, Gp);
  reduce_G<<<1024, 256, 0, stream>>>(Gp, Gh);
  compute_u<<<2, 256, 0, stream>>>(wk, bq, u);
  transpose_x<<<dim3(64, 16, 8), dim3(32, 8), 0, stream>>>(x, xh, xn);
  compute_ubias<<<BB * NB / 4, 256, 0, stream>>>(xh, u, ub);

  // YT[b][j][c] = sum_d xh[b][j][d] * G[c][d]   (single-pass fp16)
  gemm_nt<0, 1, 0><<<dim3(4, 16, 8), 256, 0, stream>>>(
      xh, CB, (long)NB * CB, Gh, nullptr, CB, 0,
      YTh, CB, (long)NB * CB, nullptr, 0, nullptr, 0, 0, CB);

  // v[b][c][n] = sum_cin wv[c][cin]*x[b][cin][n] + bv[c]
  gemm_nt<2, 1, 0><<<dim3(16, 4, 8), 256, 0, stream>>>(
      wvh, CB, 0, xh, nullptr, CB, (long)NB * CB,
      v, NB, (long)CB * NB, bv, 0, nullptr, 0, 0, CB);

  // S[z][i][j] = sum_c xh[i][c]*YTh[j][c] + ub[z][j]  -> int16 (scale 256)
  gemm_nt<1, 4, 0><<<dim3(16, 16, 8), 256, 0, stream>>>(
      xh, CB, (long)NB * CB,
      YTh, nullptr, CB, (long)NB * CB,
      Ss, NB, (long)NB * NB, ub, NB, nullptr, 0, 0, CB);

  softmax_rows<<<BB * NB, 256, 0, stream>>>(Ss, Pd);

  // out[z][ch][i] = sum_j v[z][ch][j]*Pd[z][i][j] + xn[z][ch][i]   (proven 128^2 tile)
  gemm_nt<0, 3, 0><<<dim3(16, 4, 8), 256, 0, stream>>>(
      v, NB, (long)CB * NB,
      Pd, nullptr, NB, (long)NB * NB,
      out, NB, (long)CB * NB, nullptr, 0,
      xn, NB, (long)CB * NB, NB);
}

// Round 14
// 203.099 us; speedup vs baseline: 1.0957x; 1.0424x over previous
//
#include <hip/hip_runtime.h>
#include <hip/hip_bf16.h>

typedef _Float16 half_t;
typedef _Float16 f16x8 __attribute__((ext_vector_type(8)));
typedef float f32x4 __attribute__((ext_vector_type(4)));

#define AS1 __attribute__((address_space(1)))
#define AS3 __attribute__((address_space(3)))

constexpr int CB = 512;    // channels
constexpr int NB = 2048;   // sequence length
constexpr int BB = 8;      // batch

__device__ inline f32x4 mfma16(f16x8 a, f16x8 b, f32x4 c) {
  return __builtin_amdgcn_mfma_f32_16x16x32_f16(a, b, c, 0, 0, 0);
}

// T1: XCD-aware bijective block remap (requires nwg % 8 == 0; else identity)
__device__ inline void xcd_swizzle(int& bx, int& by, int& bz) {
  const int gx = gridDim.x, gy = gridDim.y, gz = gridDim.z;
  const int nwg = gx * gy * gz;
  int lin = blockIdx.x + gx * (blockIdx.y + gy * blockIdx.z);
  if ((nwg & 7) == 0) {
    const int q = nwg >> 3;
    lin = (lin & 7) * q + (lin >> 3);
  }
  bx = lin % gx;
  int tmp = lin / gx;
  by = tmp % gy;
  bz = tmp / gy;
}

// ---------------- wv -> fp16
__global__ void convert_w(const float* __restrict__ wv, half_t* __restrict__ wvh) {
  int i = blockIdx.x * 256 + threadIdx.x;
  if (i < CB * CB) wvh[i] = (half_t)wv[i];
}

// ---------------- G partials: Gp[z][c][d] = sum_{o in chunk z} wq[o][c]*wk[o][d]
__global__ __launch_bounds__(256) void compute_G_part(const float* __restrict__ wq,
                                                      const float* __restrict__ wk,
                                                      float* __restrict__ Gp) {
  __shared__ float aq[64][68];
  __shared__ float ak[64][68];
  const int c0 = blockIdx.y * 64, d0 = blockIdx.x * 64, o0 = blockIdx.z * 64;
  const int t = threadIdx.x;
  {
    const int r = t >> 2, cbase = (t & 3) * 16;
    const float* q = wq + (size_t)(o0 + r) * CB + c0 + cbase;
    const float* k = wk + (size_t)(o0 + r) * CB + d0 + cbase;
#pragma unroll
    for (int q4 = 0; q4 < 4; q4++) {
      *(float4*)&aq[r][cbase + q4 * 4] = *(const float4*)(q + q4 * 4);
      *(float4*)&ak[r][cbase + q4 * 4] = *(const float4*)(k + q4 * 4);
    }
  }
  __syncthreads();
  const int tc = t & 15, td = t >> 4;
  float acc[4][4] = {};
#pragma unroll 8
  for (int o = 0; o < 64; o++) {
    float4 a4 = *(const float4*)&aq[o][tc * 4];
    float4 b4 = *(const float4*)&ak[o][td * 4];
    float av[4] = {a4.x, a4.y, a4.z, a4.w};
    float bv[4] = {b4.x, b4.y, b4.z, b4.w};
#pragma unroll
    for (int i = 0; i < 4; i++)
#pragma unroll
      for (int j = 0; j < 4; j++)
        acc[i][j] += av[i] * bv[j];
  }
  float* gz = Gp + (size_t)blockIdx.z * CB * CB;
#pragma unroll
  for (int i = 0; i < 4; i++) {
    int c = c0 + tc * 4 + i;
#pragma unroll
    for (int j = 0; j < 4; j++)
      gz[(size_t)c * CB + d0 + td * 4 + j] = acc[i][j];
  }
}

// ---------------- reduce 8 partials -> G fp16
__global__ void reduce_G(const float* __restrict__ Gp, half_t* __restrict__ Gh) {
  int i = blockIdx.x * 256 + threadIdx.x;
  if (i >= CB * CB) return;
  float s = 0.0f;
#pragma unroll
  for (int z = 0; z < 8; z++) s += Gp[(size_t)z * CB * CB + i];
  Gh[i] = (half_t)s;
}

// ---------------- u[d] = sum_o bq[o]*wk[o][d]
__global__ void compute_u(const float* __restrict__ wk, const float* __restrict__ bq,
                          float* __restrict__ u) {
  int d = blockIdx.x * 256 + threadIdx.x;
  if (d >= CB) return;
  float s = 0.0f;
  for (int o = 0; o < CB; o++) s += bq[o] * wk[(size_t)o * CB + d];
  u[d] = s;
}

// ---------------- ubias[row] = sum_c u[c] * xh[row][c], row in [0, B*N)
__global__ __launch_bounds__(256) void compute_ubias(const half_t* __restrict__ xh,
                                                     const float* __restrict__ u,
                                                     float* __restrict__ ub) {
  __shared__ float us[CB];
  for (int i = threadIdx.x; i < CB; i += 256) us[i] = u[i];
  __syncthreads();
  int row = blockIdx.x * 4 + (threadIdx.x >> 6);
  int lane = threadIdx.x & 63;
  f16x8 vh = *(const f16x8*)(xh + (size_t)row * CB + lane * 8);
  float s = 0.0f;
#pragma unroll
  for (int i = 0; i < 8; i++) s += us[lane * 8 + i] * (float)vh[i];
#pragma unroll
  for (int off = 32; off; off >>= 1) s += __shfl_xor(s, off);
  if (lane == 0) ub[row] = s;
}

// ---------------- x [B][C][N] fp32 -> xh [B][N][C] fp16 (transpose) + xn [B][C][N] fp16
__global__ void transpose_x(const float* __restrict__ x, half_t* __restrict__ oh,
                            half_t* __restrict__ xn) {
  __shared__ float tile[32][33];
  int b = blockIdx.z, c0 = blockIdx.y * 32, n0 = blockIdx.x * 32;
  int tx = threadIdx.x, ty = threadIdx.y;          // block (32, 8)
  const float* xb = x + (size_t)b * CB * NB;
  half_t* xnb = xn + (size_t)b * CB * NB;
#pragma unroll
  for (int r = 0; r < 4; r++) {
    float v = xb[(size_t)(c0 + ty + 8 * r) * NB + n0 + tx];
    tile[ty + 8 * r][tx] = v;
    xnb[(size_t)(c0 + ty + 8 * r) * NB + n0 + tx] = (half_t)v;
  }
  __syncthreads();
  size_t base = (size_t)b * NB * CB;
#pragma unroll
  for (int r = 0; r < 4; r++)
    oh[base + (size_t)(n0 + ty + 8 * r) * CB + c0 + tx] = (half_t)tile[tx][ty + 8 * r];
}

// ---------------- GEMM-NT (proven 128^2 2-barrier, fp16) + T1 swizzle
// BIAS: 0 none, 1 batched col-bias. EPI: 3 f32 + fp16 residual R; 4 int16 fixed-point
template <int BIAS, int EPI>
__global__ __launch_bounds__(256) void gemm_nt(
    const half_t* __restrict__ A, int lda, long sA,
    const half_t* __restrict__ Bh, int ldb, long sB,
    void* __restrict__ D, int ldd, long sD,
    const float* __restrict__ bias, long sBias,
    const half_t* __restrict__ R, int ldr, long sR,
    int K) {
  constexpr int TSZ = 128 * 32;
  __shared__ alignas(16) half_t sm[2 * 2 * TSZ];

  int bxi, byi, bzi;
  xcd_swizzle(bxi, byi, bzi);
  const int t = threadIdx.x;
  const int z = bzi;
  const half_t* Ab  = A  + (size_t)z * sA + (size_t)(byi * 128) * lda;
  const half_t* Bbh = Bh + (size_t)z * sB + (size_t)(bxi * 128) * ldb;
  const int wid = t >> 6, l15 = t & 15, hi = (t >> 4) & 3;
  const int wr = wid >> 1, wc = wid & 1;
  const int lineA = t >> 2, eoff = (t & 3) * 8;

  f32x4 acc[4][4] = {};

  auto stage = [&](int buf, int kt) {
    half_t* base = sm + buf * (2 * TSZ);
#pragma unroll
    for (int p = 0; p < 2; p++) {
      size_t goA = (size_t)(p * 64 + lineA) * lda + kt * 32 + eoff;
      size_t goB = (size_t)(p * 64 + lineA) * ldb + kt * 32 + eoff;
      int lo = p * 2048 + t * 8;
      __builtin_amdgcn_global_load_lds((const AS1 void*)(Ab + goA),  (AS3 void*)(base + lo), 16, 0, 0);
      __builtin_amdgcn_global_load_lds((const AS1 void*)(Bbh + goB), (AS3 void*)(base + TSZ + lo), 16, 0, 0);
    }
  };

  const int nt = K >> 5;
  stage(0, 0);
  __syncthreads();
  int cur = 0;
  for (int kt = 0; kt < nt; kt++) {
    if (kt + 1 < nt) stage(cur ^ 1, kt + 1);
    const half_t* bb = sm + cur * (2 * TSZ);
    f16x8 af[4], bfh[4];
#pragma unroll
    for (int f = 0; f < 4; f++) {
      af[f]  = *(const f16x8*)(bb + (wr * 64 + f * 16 + l15) * 32 + hi * 8);
      bfh[f] = *(const f16x8*)(bb + TSZ + (wc * 64 + f * 16 + l15) * 32 + hi * 8);
    }
#pragma unroll
    for (int fm = 0; fm < 4; fm++)
#pragma unroll
      for (int fn = 0; fn < 4; fn++)
        acc[fm][fn] = mfma16(af[fm], bfh[fn], acc[fm][fn]);
    __syncthreads();
    cur ^= 1;
  }

  const int row0 = byi * 128 + wr * 64;
  const int col0 = bxi * 128 + wc * 64;
#pragma unroll
  for (int fm = 0; fm < 4; fm++) {
    int rowb = row0 + fm * 16 + hi * 4;
#pragma unroll
    for (int fn = 0; fn < 4; fn++) {
      int col = col0 + fn * 16 + l15;
      float bc = (BIAS == 1) ? bias[(size_t)z * sBias + col] : 0.0f;
#pragma unroll
      for (int r = 0; r < 4; r++) {
        float val = acc[fm][fn][r] + bc;
        size_t di = (size_t)(rowb + r) * ldd + col;
        if (EPI == 3) {
          val += (float)R[(size_t)z * sR + (size_t)(rowb + r) * ldr + col];
          ((float*)D)[(size_t)z * sD + di] = val;
        } else {  // EPI == 4: int16 fixed-point, scale 256
          float sv = fminf(fmaxf(val * 256.0f, -32767.0f), 32767.0f);
          ((short*)D)[(size_t)z * sD + di] = (short)__float2int_rn(sv);
        }
      }
    }
  }
}

// ---------------- merged YT + V GEMM (one dispatch, grid (16,4,16))
// z<8  -> V:  v[z][c][n]  = sum_cin wvh[c][cin]*xh[z][n][cin] + bv[c]   (row-bias)
// z>=8 -> YT: YT[z'][j][c] = sum_d xh[z'][j][d]*Gh[c][d]                 (no bias)
__global__ __launch_bounds__(256) void gemm_vyt(
    const half_t* __restrict__ xh, const half_t* __restrict__ wvh,
    const half_t* __restrict__ Gh, const float* __restrict__ bv,
    half_t* __restrict__ v, half_t* __restrict__ YTh) {
  constexpr int TSZ = 128 * 32;
  __shared__ alignas(16) half_t sm[2 * 2 * TSZ];

  int bxi, byi, bzi;
  xcd_swizzle(bxi, byi, bzi);
  const int t = threadIdx.x;

  const half_t* Ab;
  const half_t* Bb;
  half_t* Dz;
  int ldd, row0b, col0b;
  const float* rowbias = nullptr;
  if (bzi < 8) {           // V-mode
    const int z = bzi;
    Ab = wvh + (size_t)(byi * 128) * CB;
    Bb = xh + (size_t)z * NB * CB + (size_t)(bxi * 128) * CB;
    Dz = v + (size_t)z * CB * NB;
    ldd = NB; row0b = byi * 128; col0b = bxi * 128;
    rowbias = bv;
  } else {                 // YT-mode
    const int z = bzi - 8;
    const int lin2 = byi * 16 + bxi;        // [0,64)
    const int xp = lin2 & 3, yp = lin2 >> 2;
    Ab = xh + (size_t)z * NB * CB + (size_t)(yp * 128) * CB;
    Bb = Gh + (size_t)(xp * 128) * CB;
    Dz = YTh + (size_t)z * NB * CB;
    ldd = CB; row0b = yp * 128; col0b = xp * 128;
  }

  const int wid = t >> 6, l15 = t & 15, hi = (t >> 4) & 3;
  const int wr = wid >> 1, wc = wid & 1;
  const int lineA = t >> 2, eoff = (t & 3) * 8;

  f32x4 acc[4][4] = {};

  auto stage = [&](int buf, int kt) {
    half_t* base = sm + buf * (2 * TSZ);
#pragma unroll
    for (int p = 0; p < 2; p++) {
      size_t go = (size_t)(p * 64 + lineA) * CB + kt * 32 + eoff;
      int lo = p * 2048 + t * 8;
      __builtin_amdgcn_global_load_lds((const AS1 void*)(Ab + go), (AS3 void*)(base + lo), 16, 0, 0);
      __builtin_amdgcn_global_load_lds((const AS1 void*)(Bb + go), (AS3 void*)(base + TSZ + lo), 16, 0, 0);
    }
  };

  stage(0, 0);
  __syncthreads();
  int cur = 0;
  for (int kt = 0; kt < 16; kt++) {
    if (kt + 1 < 16) stage(cur ^ 1, kt + 1);
    const half_t* bb = sm + cur * (2 * TSZ);
    f16x8 af[4], bf[4];
#pragma unroll
    for (int f = 0; f < 4; f++) {
      af[f] = *(const f16x8*)(bb + (wr * 64 + f * 16 + l15) * 32 + hi * 8);
      bf[f] = *(const f16x8*)(bb + TSZ + (wc * 64 + f * 16 + l15) * 32 + hi * 8);
    }
#pragma unroll
    for (int fm = 0; fm < 4; fm++)
#pragma unroll
      for (int fn = 0; fn < 4; fn++)
        acc[fm][fn] = mfma16(af[fm], bf[fn], acc[fm][fn]);
    __syncthreads();
    cur ^= 1;
  }

  const int row0 = row0b + wr * 64;
  const int col0 = col0b + wc * 64;
#pragma unroll
  for (int fm = 0; fm < 4; fm++) {
    int rowb = row0 + fm * 16 + hi * 4;
#pragma unroll
    for (int fn = 0; fn < 4; fn++) {
      int col = col0 + fn * 16 + l15;
#pragma unroll
      for (int r = 0; r < 4; r++) {
        float val = acc[fm][fn][r];
        if (rowbias) val += rowbias[rowb + r];
        Dz[(size_t)(rowb + r) * ldd + col] = (half_t)val;
      }
    }
  }
}

// ---------------- row softmax over S int16 [rows][2048] (scale 1/256); writes dense P fp16
struct alignas(16) H8 { half_t h[8]; };
struct alignas(16) S8 { short s[8]; };

__global__ __launch_bounds__(256) void softmax_rows(const short* __restrict__ S,
                                                    half_t* __restrict__ P) {
  const short* row = S + (size_t)blockIdx.x * NB;
  int t = threadIdx.x;
  S8 r8 = *reinterpret_cast<const S8*>(row + t * 8);
  float vals[8];
#pragma unroll
  for (int i = 0; i < 8; i++) vals[i] = (float)r8.s[i] * 0.00390625f;
  float m = vals[0];
#pragma unroll
  for (int i = 1; i < 8; i++) m = fmaxf(m, vals[i]);
#pragma unroll
  for (int off = 32; off; off >>= 1) m = fmaxf(m, __shfl_xor(m, off));
  __shared__ float redm[4], reds[4];
  if ((t & 63) == 0) redm[t >> 6] = m;
  __syncthreads();
  m = fmaxf(fmaxf(redm[0], redm[1]), fmaxf(redm[2], redm[3]));
  float e[8], s = 0.0f;
#pragma unroll
  for (int i = 0; i < 8; i++) { e[i] = __expf(vals[i] - m); s += e[i]; }
#pragma unroll
  for (int off = 32; off; off >>= 1) s += __shfl_xor(s, off);
  if ((t & 63) == 0) reds[t >> 6] = s;
  __syncthreads();
  s = reds[0] + reds[1] + reds[2] + reds[3];
  float inv = 1.0f / s;
  H8 ob;
#pragma unroll
  for (int i = 0; i < 8; i++) ob.h[i] = (half_t)(e[i] * inv);
  *reinterpret_cast<H8*>(P + (size_t)blockIdx.x * NB + t * 8) = ob;
}

// ---------------- launcher
extern "C" void kernel_launch(void* const* d_in, const int* in_sizes, int n_in,
                              void* d_out, int out_size, void* d_ws, size_t ws_size,
                              hipStream_t stream) {
  const float* x  = (const float*)d_in[0];
  const float* wq = (const float*)d_in[1];
  const float* bq = (const float*)d_in[2];
  const float* wk = (const float*)d_in[3];
  const float* wv = (const float*)d_in[5];
  const float* bv = (const float*)d_in[6];
  float* out = (float*)d_out;

  const size_t MB = 1u << 20;
  if (ws_size < 196 * MB) return;

  char* ws = (char*)d_ws;
  half_t* xh   = (half_t*)(ws + 0);            // [B][N][C]    16 MB
  half_t* YTh  = (half_t*)(ws + 16 * MB);      // [B][N][C]    16 MB
  half_t* v    = (half_t*)(ws + 32 * MB);      // [B][C][N]    16 MB
  short*  Ss   = (short*)(ws + 48 * MB);       // [8][N][N]    64 MB (int16 logits, scale 256)
  float*  Gp   = (float*)(ws + 48 * MB);       // [8][C][C]     8 MB (overlay; dead before S)
  half_t* Pd   = (half_t*)(ws + 112 * MB);     // [8][N][N]    64 MB (dense P)
  half_t* xn   = (half_t*)(ws + 176 * MB);     // [B][C][N]    16 MB (fp16 residual copy)
  half_t* Gh   = (half_t*)(ws + 192 * MB);     // [C][C]      0.5 MB
  half_t* wvh  = (half_t*)(ws + 192 * MB + 512 * 1024);  // [C][C]  0.5 MB
  float*  u    = (float*)(ws + 193 * MB);                // [C]       2 KB
  float*  ub   = (float*)(ws + 193 * MB + 256 * 1024);   // [B][N]   64 KB

  convert_w<<<1024, 256, 0, stream>>>(wv, wvh);
  compute_G_part<<<dim3(8, 8, 8), 256, 0, stream>>>(wq, wk, Gp);
  reduce_G<<<1024, 256, 0, stream>>>(Gp, Gh);
  compute_u<<<2, 256, 0, stream>>>(wk, bq, u);
  transpose_x<<<dim3(64, 16, 8), dim3(32, 8), 0, stream>>>(x, xh, xn);
  compute_ubias<<<BB * NB / 4, 256, 0, stream>>>(xh, u, ub);

  // merged: v = wvh*xh^T + bv  (z<8)  and  YT = xh*Gh^T  (z>=8)
  gemm_vyt<<<dim3(16, 4, 16), 256, 0, stream>>>(xh, wvh, Gh, bv, v, YTh);

  // S[z][i][j] = sum_c xh[i][c]*YTh[j][c] + ub[z][j]  -> int16 (scale 256)
  gemm_nt<1, 4><<<dim3(16, 16, 8), 256, 0, stream>>>(
      xh, CB, (long)NB * CB,
      YTh, CB, (long)NB * CB,
      Ss, NB, (long)NB * NB, ub, NB, nullptr, 0, 0, CB);

  softmax_rows<<<BB * NB, 256, 0, stream>>>(Ss, Pd);

  // out[z][ch][i] = sum_j v[z][ch][j]*Pd[z][i][j] + xn[z][ch][i]
  gemm_nt<0, 3><<<dim3(16, 4, 8), 256, 0, stream>>>(
      v, NB, (long)CB * NB,
      Pd, NB, (long)NB * NB,
      out, NB, (long)CB * NB, nullptr, 0,
      xn, NB, (long)CB * NB, NB);
}